// Round 6
// baseline (277.006 us; speedup 1.0000x reference)
//
#include <hip/hip_runtime.h>
#include <math.h>

#define D_MODEL 256
#define NHEAD 4
#define HEAD_DIM 64
#define SEQ 4096
#define BATCH 4
#define MROWS (BATCH * SEQ)

typedef __attribute__((ext_vector_type(8))) short short8;
typedef __attribute__((ext_vector_type(4))) short short4v;
typedef __attribute__((ext_vector_type(8))) __bf16 bf16x8;
typedef __attribute__((ext_vector_type(4))) float f32x4;

__device__ inline short f2bf(float f) {  // RNE fp32->bf16
  unsigned u = __float_as_uint(f);
  u += 0x7fffu + ((u >> 16) & 1u);
  return (short)(u >> 16);
}
__device__ inline bf16x8 as_bf8(short8 s) {
  union { short8 s; bf16x8 b; } u;
  u.s = s;
  return u.b;
}
// async global->LDS, 16B per lane; LDS dest = wave-uniform base + lane*16
__device__ __forceinline__ void g2lds16(const void* g, void* l) {
  __builtin_amdgcn_global_load_lds(
      (const __attribute__((address_space(1))) unsigned int*)g,
      (__attribute__((address_space(3))) unsigned int*)l, 16, 0, 0);
}

#define QSCALE 0.1803368801111204f  /* 0.125 * log2(e): exp2-domain scores */

// ============ Kernel 1: LN1 + QKV GEMM + W1/W2 image conversion ============
// grid (128, 7). y<6: m-tile = 128 rows, which=y>>1 in {Q,K,V}, n0=(y&1)*128.
// LN1 computed in-block into LDS Xf (bf16, XOR-swizzled by row&7 -> all frag
// reads hit 8 distinct bank-quads per 8 lanes). W staged per k-step with
// inline fp32->bf16 cvt, XOR-swizzled by row&3. y==6: convert W1/W2 into
// bf16 k-step images (XOR by n&3) for ffn_ln's global_load_lds staging.
__global__ __launch_bounds__(256) void qkv_ln(
    const float* __restrict__ x, const float* __restrict__ g1,
    const float* __restrict__ b1, const float* __restrict__ Wq,
    const float* __restrict__ Wk, const float* __restrict__ Wv,
    const float* __restrict__ W1, const float* __restrict__ W2,
    short* __restrict__ qo, short* __restrict__ kimg,
    short* __restrict__ vimg, short* __restrict__ w1img,
    short* __restrict__ w2img) {
  const int t = threadIdx.x;
  if (blockIdx.y == 6) {  // W1/W2 -> swizzled bf16 k-step images
    int xid = blockIdx.x;
    const float* src = (xid >> 6) ? W2 : W1;
    short* dst = (xid >> 6) ? w2img : w1img;
    int idx = ((xid & 63) * 256 + t) * 4;
    int n = idx >> 8, k = idx & 255;
    float4 f = *(const float4*)(src + idx);
    short4v o = {f2bf(f.x), f2bf(f.y), f2bf(f.z), f2bf(f.w)};
    size_t off = (size_t)(k >> 5) * 8192 + n * 32 +
                 ((((k & 31) >> 3) ^ (n & 3)) * 8) + (k & 7);
    *(short4v*)(dst + off) = o;
    return;
  }
  __shared__ __align__(16) short Xf[128 * 256];  // 64 KB
  __shared__ __align__(16) short Ws[128 * 32];   // 8 KB
  const int lane = t & 63, l15 = lane & 15, quad = lane >> 4;
  const int wv = t >> 6, wm = wv & 1, wn = wv >> 1;
  const int m0 = blockIdx.x * 128;
  const int which = blockIdx.y >> 1;
  const int n0 = (blockIdx.y & 1) * 128;
  const float* Wsrc = which == 0 ? Wq : which == 1 ? Wk : Wv;

  // ---- LN1: 2 threads per row, two-pass ----
  {
    int r = t >> 1, half = t & 1;
    const float* xr = x + (size_t)(m0 + r) * D_MODEL + half * 128;
    const float* gp = g1 + half * 128;
    const float* bp = b1 + half * 128;
    float s = 0.f, ss = 0.f;
#pragma unroll
    for (int i = 0; i < 32; i++) {
      float4 f = *(const float4*)(xr + i * 4);
      s += f.x + f.y + f.z + f.w;
      ss += f.x * f.x + f.y * f.y + f.z * f.z + f.w * f.w;
    }
    s += __shfl_xor(s, 1);
    ss += __shfl_xor(ss, 1);
    float mu = s * (1.0f / D_MODEL);
    float rstd = rsqrtf(ss * (1.0f / D_MODEL) - mu * mu + 1e-5f);
#pragma unroll
    for (int gI = 0; gI < 16; gI++) {
      float4 a = *(const float4*)(xr + gI * 8);
      float4 c = *(const float4*)(xr + gI * 8 + 4);
      float4 ga = *(const float4*)(gp + gI * 8);
      float4 gc = *(const float4*)(gp + gI * 8 + 4);
      float4 ba = *(const float4*)(bp + gI * 8);
      float4 bc = *(const float4*)(bp + gI * 8 + 4);
      short8 o = {f2bf((a.x - mu) * rstd * ga.x + ba.x),
                  f2bf((a.y - mu) * rstd * ga.y + ba.y),
                  f2bf((a.z - mu) * rstd * ga.z + ba.z),
                  f2bf((a.w - mu) * rstd * ga.w + ba.w),
                  f2bf((c.x - mu) * rstd * gc.x + bc.x),
                  f2bf((c.y - mu) * rstd * gc.y + bc.y),
                  f2bf((c.z - mu) * rstd * gc.z + bc.z),
                  f2bf((c.w - mu) * rstd * gc.w + bc.w)};
      int cg = half * 16 + gI;
      *(short8*)&Xf[r * 256 + ((cg ^ (r & 7)) * 8)] = o;
    }
  }
  f32x4 acc[4][4];
#pragma unroll
  for (int i = 0; i < 4; i++)
#pragma unroll
    for (int j = 0; j < 4; j++) acc[i][j] = (f32x4){0.f, 0.f, 0.f, 0.f};
  __syncthreads();

  // ---- k-loop: stage W (cvt inline, XOR row&3), X frags from Xf ----
  for (int ks = 0; ks < 8; ks++) {
    {
      int r = t >> 1, hk = t & 1;
      const float* wp = Wsrc + (size_t)(n0 + r) * D_MODEL + ks * 32 + hk * 16;
      float4 f0 = *(const float4*)(wp);
      float4 f1 = *(const float4*)(wp + 4);
      float4 f2v = *(const float4*)(wp + 8);
      float4 f3v = *(const float4*)(wp + 12);
      short8 o0 = {f2bf(f0.x), f2bf(f0.y), f2bf(f0.z), f2bf(f0.w),
                   f2bf(f1.x), f2bf(f1.y), f2bf(f1.z), f2bf(f1.w)};
      short8 o1 = {f2bf(f2v.x), f2bf(f2v.y), f2bf(f2v.z), f2bf(f2v.w),
                   f2bf(f3v.x), f2bf(f3v.y), f2bf(f3v.z), f2bf(f3v.w)};
      int g0 = 2 * hk;
      *(short8*)&Ws[r * 32 + (((g0 + 0) ^ (r & 3)) * 8)] = o0;
      *(short8*)&Ws[r * 32 + (((g0 + 1) ^ (r & 3)) * 8)] = o1;
    }
    __syncthreads();
    bf16x8 fx[4], fw[4];
#pragma unroll
    for (int i = 0; i < 4; i++) {
      fx[i] = as_bf8(*(short8*)&Xf[(wm * 64 + i * 16 + l15) * 256 +
                                   (((ks * 4 + quad) ^ (l15 & 7)) * 8)]);
      fw[i] = as_bf8(*(short8*)&Ws[(wn * 64 + i * 16 + l15) * 32 +
                                   ((quad ^ (l15 & 3)) * 8)]);
    }
    if (which == 2) {
#pragma unroll
      for (int mt = 0; mt < 4; mt++)
#pragma unroll
        for (int nt = 0; nt < 4; nt++)
          acc[mt][nt] = __builtin_amdgcn_mfma_f32_16x16x32_bf16(fx[mt], fw[nt], acc[mt][nt], 0, 0, 0);
    } else {
#pragma unroll
      for (int mt = 0; mt < 4; mt++)
#pragma unroll
        for (int nt = 0; nt < 4; nt++)
          acc[mt][nt] = __builtin_amdgcn_mfma_f32_16x16x32_bf16(fw[nt], fx[mt], acc[mt][nt], 0, 0, 0);
    }
    __syncthreads();
  }

  // ---- epilogues: Q (scaled, row-major) / K image / VT image ----
#pragma unroll
  for (int mt = 0; mt < 4; mt++)
#pragma unroll
    for (int nt = 0; nt < 4; nt++) {
      f32x4 v = acc[mt][nt];
      if (which == 2) {  // VT image: D[m=s][n=feature]
        int n = n0 + wn * 64 + nt * 16 + l15;
        int mr = m0 + wm * 64 + mt * 16 + quad * 4;
        int b = mr >> 12, s = mr & 4095, h = n >> 6, d = n & 63;
        size_t off = ((size_t)(b * NHEAD + h) * 64 + (s >> 6)) * 4096 +
                     (size_t)d * 64 + ((((s & 63) >> 3) ^ (d & 7)) * 8) + (s & 7);
        short4v o = {f2bf(v[0]), f2bf(v[1]), f2bf(v[2]), f2bf(v[3])};
        *(short4v*)(vimg + off) = o;
      } else {
        int m = m0 + wm * 64 + mt * 16 + l15;
        int nb = n0 + wn * 64 + nt * 16 + quad * 4;
        if (which == 0) {
          v *= QSCALE;
          short4v o = {f2bf(v[0]), f2bf(v[1]), f2bf(v[2]), f2bf(v[3])};
          *(short4v*)(qo + (size_t)m * D_MODEL + nb) = o;
        } else {  // K image
          int b = m >> 12, s = m & 4095, h = nb >> 6, d = nb & 63;
          size_t off = ((size_t)(b * NHEAD + h) * 64 + (s >> 6)) * 4096 +
                       (size_t)(s & 63) * 64 + (((d >> 3) ^ (s & 7)) * 8) + (d & 7);
          short4v o = {f2bf(v[0]), f2bf(v[1]), f2bf(v[2]), f2bf(v[3])};
          *(short4v*)(kimg + off) = o;
        }
      }
    }
}

// ============ Kernel 3: LN2 + FFN (f1 LDS-resident) + residual =============
// grid (512): 32-row m-tiles -> 2 blocks/CU. W1/W2 staged from pre-swizzled
// bf16 images via global_load_lds. Hs/F1s stride 264 (33 mod 8 = 1 ->
// conflict-free b128 frag reads).
__global__ __launch_bounds__(256) void ffn_ln(
    const float* __restrict__ xt, const float* __restrict__ g2,
    const float* __restrict__ b2, const short* __restrict__ w1img,
    const short* __restrict__ w2img, const float* __restrict__ bf1,
    const float* __restrict__ bf2, float* __restrict__ out) {
  __shared__ __align__(16) short Hs[32 * 264];   // 16.5 KB
  __shared__ __align__(16) short Ws[256 * 32];   // 16 KB (g2lds image copy)
  __shared__ __align__(16) short F1s[32 * 264];  // 16.5 KB
  const int t = threadIdx.x, lane = t & 63, l15 = lane & 15, quad = lane >> 4;
  const int w = t >> 6;
  const int m0 = blockIdx.x * 32;

  // ---- LN2: 8 threads per row, two-pass ----
  {
    int r = t >> 3, c8 = t & 7;
    const float* xr = xt + (size_t)(m0 + r) * D_MODEL + c8 * 32;
    const float* gp = g2 + c8 * 32;
    const float* bp = b2 + c8 * 32;
    float s = 0.f, ss = 0.f;
#pragma unroll
    for (int i = 0; i < 8; i++) {
      float4 f = *(const float4*)(xr + i * 4);
      s += f.x + f.y + f.z + f.w;
      ss += f.x * f.x + f.y * f.y + f.z * f.z + f.w * f.w;
    }
#pragma unroll
    for (int off = 1; off < 8; off <<= 1) {
      s += __shfl_xor(s, off);
      ss += __shfl_xor(ss, off);
    }
    float mu = s * (1.0f / D_MODEL);
    float rstd = rsqrtf(ss * (1.0f / D_MODEL) - mu * mu + 1e-5f);
#pragma unroll
    for (int gI = 0; gI < 4; gI++) {
      float4 a = *(const float4*)(xr + gI * 8);
      float4 c = *(const float4*)(xr + gI * 8 + 4);
      float4 ga = *(const float4*)(gp + gI * 8);
      float4 gc = *(const float4*)(gp + gI * 8 + 4);
      float4 ba = *(const float4*)(bp + gI * 8);
      float4 bc = *(const float4*)(bp + gI * 8 + 4);
      short8 o = {f2bf((a.x - mu) * rstd * ga.x + ba.x),
                  f2bf((a.y - mu) * rstd * ga.y + ba.y),
                  f2bf((a.z - mu) * rstd * ga.z + ba.z),
                  f2bf((a.w - mu) * rstd * ga.w + ba.w),
                  f2bf((c.x - mu) * rstd * gc.x + bc.x),
                  f2bf((c.y - mu) * rstd * gc.y + bc.y),
                  f2bf((c.z - mu) * rstd * gc.z + bc.z),
                  f2bf((c.w - mu) * rstd * gc.w + bc.w)};
      *(short8*)&Hs[r * 264 + c8 * 32 + gI * 8] = o;
    }
  }
  // ---- GEMM1: D1[n1][m] = W1 . h^T ; wave owns 64 n1 ----
  f32x4 acc1[4][2];
#pragma unroll
  for (int i = 0; i < 4; i++)
#pragma unroll
    for (int j = 0; j < 2; j++) acc1[i][j] = (f32x4){0.f, 0.f, 0.f, 0.f};
  __syncthreads();

  for (int ks = 0; ks < 8; ks++) {
#pragma unroll
    for (int i = 0; i < 4; i++) {
      int c = i * 4 + w;
      g2lds16(w1img + (size_t)ks * 8192 + c * 512 + lane * 8, &Ws[c * 512]);
    }
    __syncthreads();
    bf16x8 fh[2], fw1[4];
#pragma unroll
    for (int i = 0; i < 2; i++)
      fh[i] = as_bf8(*(short8*)&Hs[(i * 16 + l15) * 264 + ks * 32 + quad * 8]);
#pragma unroll
    for (int i = 0; i < 4; i++)
      fw1[i] = as_bf8(*(short8*)&Ws[(w * 64 + i * 16 + l15) * 32 +
                                    ((quad ^ (l15 & 3)) * 8)]);
#pragma unroll
    for (int nt = 0; nt < 4; nt++)
#pragma unroll
      for (int mt = 0; mt < 2; mt++)
        acc1[nt][mt] = __builtin_amdgcn_mfma_f32_16x16x32_bf16(fw1[nt], fh[mt], acc1[nt][mt], 0, 0, 0);
    __syncthreads();
  }
  // ---- f1 = relu(D1 + bf1) -> F1s[m][n1] ----
#pragma unroll
  for (int nt = 0; nt < 4; nt++)
#pragma unroll
    for (int mt = 0; mt < 2; mt++) {
      int n1 = w * 64 + nt * 16 + quad * 4;
      float4 bv = *(const float4*)(bf1 + n1);
      f32x4 v = acc1[nt][mt];
      short4v o = {f2bf(fmaxf(v[0] + bv.x, 0.f)), f2bf(fmaxf(v[1] + bv.y, 0.f)),
                   f2bf(fmaxf(v[2] + bv.z, 0.f)), f2bf(fmaxf(v[3] + bv.w, 0.f))};
      *(short4v*)&F1s[(mt * 16 + l15) * 264 + n1] = o;
    }
  __syncthreads();

  // ---- GEMM2: D2[m][n2] = f1 . W2^T ; wave owns 64 n2 ----
  f32x4 a2[2][4];
#pragma unroll
  for (int i = 0; i < 2; i++)
#pragma unroll
    for (int j = 0; j < 4; j++) a2[i][j] = (f32x4){0.f, 0.f, 0.f, 0.f};

  for (int ks = 0; ks < 8; ks++) {
#pragma unroll
    for (int i = 0; i < 4; i++) {
      int c = i * 4 + w;
      g2lds16(w2img + (size_t)ks * 8192 + c * 512 + lane * 8, &Ws[c * 512]);
    }
    __syncthreads();
    bf16x8 ff[2], fw2[4];
#pragma unroll
    for (int i = 0; i < 2; i++)
      ff[i] = as_bf8(*(short8*)&F1s[(i * 16 + l15) * 264 + ks * 32 + quad * 8]);
#pragma unroll
    for (int i = 0; i < 4; i++)
      fw2[i] = as_bf8(*(short8*)&Ws[(w * 64 + i * 16 + l15) * 32 +
                                    ((quad ^ (l15 & 3)) * 8)]);
#pragma unroll
    for (int mt = 0; mt < 2; mt++)
#pragma unroll
      for (int nt = 0; nt < 4; nt++)
        a2[mt][nt] = __builtin_amdgcn_mfma_f32_16x16x32_bf16(ff[mt], fw2[nt], a2[mt][nt], 0, 0, 0);
    __syncthreads();
  }
  // ---- out = D2 + bf2 + xt ----
#pragma unroll
  for (int mt = 0; mt < 2; mt++)
#pragma unroll
    for (int nt = 0; nt < 4; nt++) {
      int n2 = w * 64 + nt * 16 + l15;
      int mbase = m0 + mt * 16 + quad * 4;
      float bv = bf2[n2];
      f32x4 v = a2[mt][nt];
#pragma unroll
      for (int r = 0; r < 4; r++) {
        size_t a = (size_t)(mbase + r) * D_MODEL + n2;
        out[a] = v[r] + bv + xt[a];
      }
    }
}

// ---------------- MFMA flash attention v3 (unchanged, measured 100 us) -----
__global__ __launch_bounds__(256) void attn_v3(const short* __restrict__ qb,
                                               const short* __restrict__ kimg,
                                               const short* __restrict__ vimg,
                                               const float* __restrict__ x,
                                               float* __restrict__ xt) {
  __shared__ __align__(16) short Ks[2 * 4096];
  __shared__ __align__(16) short Vs[2 * 4096];
  __shared__ __align__(16) short Pt[4][16 * 136];

  const int t = threadIdx.x, lane = t & 63, w = t >> 6;
  const int quad = lane >> 4, l15 = lane & 15;
  const int pair = blockIdx.x;
  const int bh = blockIdx.y, b = bh >> 2, h = bh & 3;
  const int ldsoff = __builtin_amdgcn_readfirstlane(w * 512);
  const short* kb_bh = kimg + (size_t)bh * 64 * 4096;
  const short* vb_bh = vimg + (size_t)bh * 64 * 4096;

  for (int tile = 0; tile < 2; tile++) {
    const int qt = tile == 0 ? 63 - pair : pair;
    const int q0 = qt * 64;
    const int qrow = q0 + w * 16 + l15;
    const int wq_lo = q0 + w * 16, wq_hi = wq_lo + 15;

    bf16x8 qf0, qf1;
    {
      const short* qp = qb + ((size_t)(b * SEQ + qrow)) * D_MODEL + h * HEAD_DIM + quad * 8;
      qf0 = as_bf8(*(const short8*)qp);
      qf1 = as_bf8(*(const short8*)(qp + 32));
    }
    f32x4 oacc[4];
#pragma unroll
    for (int i = 0; i < 4; i++) oacc[i] = (f32x4){0.f, 0.f, 0.f, 0.f};
    float mrun = -1e30f, lrun = 0.f;

    const int niter = (qt + 2) >> 1;
    for (int it = 0; it < niter; it++) {
      const int j0 = it * 128;
      const short* kc_base = kb_bh + (size_t)(2 * it) * 4096;
      const short* vc_base = vb_bh + (size_t)(2 * it) * 4096;
#pragma unroll
      for (int i = 0; i < 4; i++) {
        g2lds16(kc_base + i * 2048 + t * 8, &Ks[i * 2048 + ldsoff]);
        g2lds16(vc_base + i * 2048 + t * 8, &Vs[i * 2048 + ldsoff]);
      }
      __syncthreads();

      const bool half1 = (j0 + 64) <= wq_hi;
      const int kcmax = half1 ? 8 : 4;
      f32x4 st[8];
#pragma unroll
      for (int kc = 0; kc < 8; kc++) {
        if (kc < kcmax) {
          int key = kc * 16 + l15;
          int img = (key >> 6) * 4096, r = key & 63;
          f32x4 z = (f32x4){0.f, 0.f, 0.f, 0.f};
          bf16x8 kf0 = as_bf8(*(short8*)&Ks[img + r * 64 + ((quad ^ (r & 7)) * 8)]);
          bf16x8 kf1 = as_bf8(*(short8*)&Ks[img + r * 64 + (((4 + quad) ^ (r & 7)) * 8)]);
          z = __builtin_amdgcn_mfma_f32_16x16x32_bf16(kf0, qf0, z, 0, 0, 0);
          z = __builtin_amdgcn_mfma_f32_16x16x32_bf16(kf1, qf1, z, 0, 0, 0);
          st[kc] = z;
        } else {
          st[kc] = (f32x4){-1e30f, -1e30f, -1e30f, -1e30f};
        }
      }
      if (j0 + 127 > wq_lo) {
#pragma unroll
        for (int kc = 0; kc < 8; kc++)
#pragma unroll
          for (int r = 0; r < 4; r++)
            if (j0 + kc * 16 + quad * 4 + r > qrow) st[kc][r] = -1e30f;
      }
      float smax = -1e30f;
#pragma unroll
      for (int kc = 0; kc < 8; kc++)
#pragma unroll
        for (int r = 0; r < 4; r++) smax = fmaxf(smax, st[kc][r]);
      smax = fmaxf(smax, __shfl_xor(smax, 16));
      smax = fmaxf(smax, __shfl_xor(smax, 32));
      float mn = fmaxf(mrun, smax);
      float alpha = __builtin_amdgcn_exp2f(mrun - mn);
      mrun = mn;
      float psum = 0.f;
#pragma unroll
      for (int kc = 0; kc < 8; kc++) {
        if (kc < kcmax) {
#pragma unroll
          for (int r = 0; r < 4; r++) {
            float p = __builtin_amdgcn_exp2f(st[kc][r] - mn);
            st[kc][r] = p;
            psum += p;
          }
        }
      }
      psum += __shfl_xor(psum, 16);
      psum += __shfl_xor(psum, 32);
      lrun = lrun * alpha + psum;
#pragma unroll
      for (int i = 0; i < 4; i++) oacc[i] *= alpha;
#pragma unroll
      for (int kc = 0; kc < 8; kc++) {
        if (kc < kcmax) {
          unsigned u0 = (__float_as_uint(st[kc][0]) >> 16) | (__float_as_uint(st[kc][1]) & 0xffff0000u);
          unsigned u1 = (__float_as_uint(st[kc][2]) >> 16) | (__float_as_uint(st[kc][3]) & 0xffff0000u);
          uint2 uu = {u0, u1};
          *(uint2*)&Pt[w][l15 * 136 + kc * 16 + quad * 4] = uu;
        }
      }
      const int fimax = half1 ? 4 : 2;
      bf16x8 pf[4];
#pragma unroll
      for (int fi = 0; fi < 4; fi++)
        if (fi < fimax) pf[fi] = as_bf8(*(short8*)&Pt[w][l15 * 136 + fi * 32 + quad * 8]);
#pragma unroll
      for (int dt = 0; dt < 4; dt++) {
        f32x4 o = oacc[dt];
        int d = dt * 16 + l15;
#pragma unroll
        for (int fi = 0; fi < 4; fi++) {
          if (fi < fimax) {
            bf16x8 vf = as_bf8(*(short8*)&Vs[(fi >> 1) * 4096 + d * 64 +
                                             ((((fi & 1) * 4 + quad) ^ (d & 7)) * 8)]);
            o = __builtin_amdgcn_mfma_f32_16x16x32_bf16(vf, pf[fi], o, 0, 0, 0);
          }
        }
        oacc[dt] = o;
      }
      __syncthreads();
    }

    float inv = 1.0f / lrun;
    size_t rowb = ((size_t)(b * SEQ + qrow)) * D_MODEL + h * HEAD_DIM;
#pragma unroll
    for (int dt = 0; dt < 4; dt++) {
      size_t a = rowb + dt * 16 + quad * 4;
      float4 xv = *(const float4*)(x + a);
      float4 o = make_float4(oacc[dt][0] * inv + xv.x, oacc[dt][1] * inv + xv.y,
                             oacc[dt][2] * inv + xv.z, oacc[dt][3] * inv + xv.w);
      *(float4*)(xt + a) = o;
    }
  }
}

// ---------------------------------------------------------------------------
extern "C" void kernel_launch(void* const* d_in, const int* in_sizes, int n_in,
                              void* d_out, int out_size, void* d_ws,
                              size_t ws_size, hipStream_t stream) {
  const float* x = (const float*)d_in[0];
  const float* Wq = (const float*)d_in[1];
  const float* Wk = (const float*)d_in[2];
  const float* Wv = (const float*)d_in[3];
  const float* g1 = (const float*)d_in[4];
  const float* b1 = (const float*)d_in[5];
  const float* g2 = (const float*)d_in[6];
  const float* b2 = (const float*)d_in[7];
  const float* W1 = (const float*)d_in[8];
  const float* bf1 = (const float*)d_in[9];
  const float* W2 = (const float*)d_in[10];
  const float* bf2 = (const float*)d_in[11];
  float* out = (float*)d_out;

  char* ws = (char*)d_ws;
  float* xt = (float*)ws;                       // 16 MB
  short* q_bf = (short*)(ws + (16u << 20));     // 8 MB
  short* kimg = (short*)(ws + (24u << 20));     // 8 MB
  short* vimg = (short*)(ws + (32u << 20));     // 8 MB
  short* w1img = (short*)(ws + (40u << 20));    // 128 KB
  short* w2img = w1img + 65536;                 // 128 KB

  dim3 blk(256);
  qkv_ln<<<dim3(128, 7), blk, 0, stream>>>(x, g1, b1, Wq, Wk, Wv, W1, W2,
                                           q_bf, kimg, vimg, w1img, w2img);
  attn_v3<<<dim3(32, 16), blk, 0, stream>>>(q_bf, kimg, vimg, x, xt);
  ffn_ln<<<dim3(512), blk, 0, stream>>>(xt, g2, b2, w1img, w2img, bf1, bf2, out);
}

// Round 7
// 255.756 us; speedup vs baseline: 1.0831x; 1.0831x over previous
//
#include <hip/hip_runtime.h>
#include <math.h>

#define D_MODEL 256
#define NHEAD 4
#define HEAD_DIM 64
#define SEQ 4096
#define BATCH 4
#define MROWS (BATCH * SEQ)

typedef __attribute__((ext_vector_type(8))) short short8;
typedef __attribute__((ext_vector_type(4))) short short4v;
typedef __attribute__((ext_vector_type(8))) __bf16 bf16x8;
typedef __attribute__((ext_vector_type(4))) float f32x4;

__device__ inline short f2bf(float f) {  // RNE fp32->bf16
  unsigned u = __float_as_uint(f);
  u += 0x7fffu + ((u >> 16) & 1u);
  return (short)(u >> 16);
}
__device__ inline bf16x8 as_bf8(short8 s) {
  union { short8 s; bf16x8 b; } u;
  u.s = s;
  return u.b;
}
// async global->LDS, 16B per lane; LDS dest = wave-uniform base + lane*16
__device__ __forceinline__ void g2lds16(const void* g, void* l) {
  __builtin_amdgcn_global_load_lds(
      (const __attribute__((address_space(1))) unsigned int*)g,
      (__attribute__((address_space(3))) unsigned int*)l, 16, 0, 0);
}

#define QSCALE 0.1803368801111204f  /* 0.125 * log2(e): exp2-domain scores */

// ---- weight cvt fp32->bf16, row-major with XOR-swizzled 16B groups --------
// element (n,k) -> n*256 + (k>>5)*32 + (((k>>3)&3) ^ (n&3))*8 + (k&7)
__global__ __launch_bounds__(256) void wcvt(const float* __restrict__ s0, const float* __restrict__ s1,
                                            const float* __restrict__ s2, const float* __restrict__ s3,
                                            const float* __restrict__ s4, short* __restrict__ d0,
                                            short* __restrict__ d1, short* __restrict__ d2,
                                            short* __restrict__ d3, short* __restrict__ d4) {
  int mat = blockIdx.x >> 5;
  int e = ((blockIdx.x & 31) * 256 + threadIdx.x) * 8;
  const float* s = mat == 0 ? s0 : mat == 1 ? s1 : mat == 2 ? s2 : mat == 3 ? s3 : s4;
  short* d = mat == 0 ? d0 : mat == 1 ? d1 : mat == 2 ? d2 : mat == 3 ? d3 : d4;
  int n = e >> 8, k0 = e & 255;
  float4 f0 = *(const float4*)(s + n * 256 + k0);
  float4 f1 = *(const float4*)(s + n * 256 + k0 + 4);
  short8 o = {f2bf(f0.x), f2bf(f0.y), f2bf(f0.z), f2bf(f0.w),
              f2bf(f1.x), f2bf(f1.y), f2bf(f1.z), f2bf(f1.w)};
  int chunk = k0 >> 5, g = (k0 >> 3) & 3;
  *(short8*)(d + n * 256 + chunk * 32 + ((g ^ (n & 3)) * 8)) = o;
}

// ---- LayerNorm fp32 -> bf16 swizzled rows (8 rows/block, 32 thr/row) ------
__global__ __launch_bounds__(256) void ln_sw(const float* __restrict__ x,
                                             const float* __restrict__ g,
                                             const float* __restrict__ b,
                                             short* __restrict__ o) {
  int r = threadIdx.x >> 5, c8 = threadIdx.x & 31;
  int row = blockIdx.x * 8 + r;
  const float* xr = x + (size_t)row * D_MODEL + c8 * 8;
  float4 a = *(const float4*)xr;
  float4 c = *(const float4*)(xr + 4);
  float s = a.x + a.y + a.z + a.w + c.x + c.y + c.z + c.w;
#pragma unroll
  for (int off = 16; off > 0; off >>= 1) s += __shfl_xor(s, off);
  float mu = s * (1.0f / D_MODEL);
  float d0 = a.x - mu, d1 = a.y - mu, d2 = a.z - mu, d3 = a.w - mu;
  float d4 = c.x - mu, d5 = c.y - mu, d6 = c.z - mu, d7 = c.w - mu;
  float ss = d0 * d0 + d1 * d1 + d2 * d2 + d3 * d3 + d4 * d4 + d5 * d5 + d6 * d6 + d7 * d7;
#pragma unroll
  for (int off = 16; off > 0; off >>= 1) ss += __shfl_xor(ss, off);
  float rstd = rsqrtf(ss * (1.0f / D_MODEL) + 1e-5f);
  float4 ga = *(const float4*)(g + c8 * 8);
  float4 gc = *(const float4*)(g + c8 * 8 + 4);
  float4 ba = *(const float4*)(b + c8 * 8);
  float4 bc = *(const float4*)(b + c8 * 8 + 4);
  short8 ov = {f2bf(d0 * rstd * ga.x + ba.x), f2bf(d1 * rstd * ga.y + ba.y),
               f2bf(d2 * rstd * ga.z + ba.z), f2bf(d3 * rstd * ga.w + ba.w),
               f2bf(d4 * rstd * gc.x + bc.x), f2bf(d5 * rstd * gc.y + bc.y),
               f2bf(d6 * rstd * gc.z + bc.z), f2bf(d7 * rstd * gc.w + bc.w)};
  int chunk = c8 >> 2, gr = c8 & 3;
  *(short8*)(o + (size_t)row * D_MODEL + chunk * 32 + ((gr ^ (row & 3)) * 8)) = ov;
}

// ---- QKV one-shot GEMM: stage full K=256 panels once, no k-loop -----------
// grid (256, 12): which = y>>2 in {Q,K,V}, n0 = (y&3)*64. 64x64 tile,
// 4 waves of 32x32. K/VT written in attention chunk-image order.
__global__ __launch_bounds__(256) void qkv_oneshot(
    const short* __restrict__ Wqi, const short* __restrict__ Wki,
    const short* __restrict__ Wvi, const short* __restrict__ Xn,
    short* __restrict__ qo, short* __restrict__ kimg, short* __restrict__ vimg) {
  __shared__ __align__(16) short Xs[64 * 256];  // 32 KB
  __shared__ __align__(16) short Ws[64 * 256];  // 32 KB
  const int t = threadIdx.x, lane = t & 63, w = t >> 6;
  const int l15 = lane & 15, quad = lane >> 4;
  const int wm = w & 1, wn = w >> 1;
  const int m0 = blockIdx.x * 64;
  const int which = blockIdx.y >> 2;
  const int n0 = (blockIdx.y & 3) * 64;
  const short* Wb = which == 0 ? Wqi : which == 1 ? Wki : Wvi;

#pragma unroll
  for (int j = 0; j < 8; j++) {
    int so = __builtin_amdgcn_readfirstlane((w * 8 + j) * 512);
    g2lds16(Xn + (size_t)m0 * D_MODEL + so + lane * 8, &Xs[so]);
    g2lds16(Wb + (size_t)n0 * D_MODEL + so + lane * 8, &Ws[so]);
  }
  __syncthreads();

  f32x4 acc[2][2];
#pragma unroll
  for (int i = 0; i < 2; i++)
#pragma unroll
    for (int j = 0; j < 2; j++) acc[i][j] = (f32x4){0.f, 0.f, 0.f, 0.f};

#pragma unroll
  for (int kf = 0; kf < 8; kf++) {
    bf16x8 fx[2], fw[2];
#pragma unroll
    for (int i = 0; i < 2; i++) {
      fx[i] = as_bf8(*(short8*)&Xs[(wm * 32 + i * 16 + l15) * 256 + kf * 32 +
                                   ((quad ^ (l15 & 3)) * 8)]);
      fw[i] = as_bf8(*(short8*)&Ws[(wn * 32 + i * 16 + l15) * 256 + kf * 32 +
                                   ((quad ^ (l15 & 3)) * 8)]);
    }
    if (which == 2) {
#pragma unroll
      for (int mt = 0; mt < 2; mt++)
#pragma unroll
        for (int nt = 0; nt < 2; nt++)
          acc[mt][nt] = __builtin_amdgcn_mfma_f32_16x16x32_bf16(fx[mt], fw[nt], acc[mt][nt], 0, 0, 0);
    } else {
#pragma unroll
      for (int mt = 0; mt < 2; mt++)
#pragma unroll
        for (int nt = 0; nt < 2; nt++)
          acc[mt][nt] = __builtin_amdgcn_mfma_f32_16x16x32_bf16(fw[nt], fx[mt], acc[mt][nt], 0, 0, 0);
    }
  }

#pragma unroll
  for (int mt = 0; mt < 2; mt++)
#pragma unroll
    for (int nt = 0; nt < 2; nt++) {
      f32x4 v = acc[mt][nt];
      if (which == 2) {  // VT image: D[m=s][n=feature]
        int n = n0 + wn * 32 + nt * 16 + l15;
        int mr = m0 + wm * 32 + mt * 16 + quad * 4;
        int b = mr >> 12, s = mr & 4095, h = n >> 6, d = n & 63;
        size_t off = ((size_t)(b * NHEAD + h) * 64 + (s >> 6)) * 4096 +
                     (size_t)d * 64 + ((((s & 63) >> 3) ^ (d & 7)) * 8) + (s & 7);
        short4v o = {f2bf(v[0]), f2bf(v[1]), f2bf(v[2]), f2bf(v[3])};
        *(short4v*)(vimg + off) = o;
      } else {
        int m = m0 + wm * 32 + mt * 16 + l15;
        int nb = n0 + wn * 32 + nt * 16 + quad * 4;
        if (which == 0) {  // Q row-major, exp2-domain scale folded in
          v *= QSCALE;
          short4v o = {f2bf(v[0]), f2bf(v[1]), f2bf(v[2]), f2bf(v[3])};
          *(short4v*)(qo + (size_t)m * D_MODEL + nb) = o;
        } else {  // K image
          int b = m >> 12, s = m & 4095, h = nb >> 6, d = nb & 63;
          size_t off = ((size_t)(b * NHEAD + h) * 64 + (s >> 6)) * 4096 +
                       (size_t)(s & 63) * 64 + (((d >> 3) ^ (s & 7)) * 8) + (d & 7);
          short4v o = {f2bf(v[0]), f2bf(v[1]), f2bf(v[2]), f2bf(v[3])};
          *(short4v*)(kimg + off) = o;
        }
      }
    }
}

// ---- FFN one-shot: out = relu(h@W1^T+b1)@W2^T + b2 + xt -------------------
// Block = 64 rows, grid 256 (1/CU). f1 LDS-resident. W1/W2 staged in 64 KB
// halves (129.75 KB LDS total). 6 barriers instead of 32.
__global__ __launch_bounds__(256) void ffn_oneshot(
    const short* __restrict__ w1i, const short* __restrict__ w2i,
    const short* __restrict__ Hsw, const float* __restrict__ bf1,
    const float* __restrict__ bf2, const float* __restrict__ xt,
    float* __restrict__ out) {
  __shared__ __align__(16) short Hs[64 * 256];    // 32 KB
  __shared__ __align__(16) short Wsh[128 * 256];  // 64 KB
  __shared__ __align__(16) short F1s[64 * 264];   // 33.75 KB
  const int t = threadIdx.x, lane = t & 63, w = t >> 6;
  const int l15 = lane & 15, quad = lane >> 4;
  const int mh = w & 1, nq = w >> 1;
  const int m0 = blockIdx.x * 64;

#pragma unroll
  for (int j = 0; j < 8; j++) {
    int so = __builtin_amdgcn_readfirstlane((w * 8 + j) * 512);
    g2lds16(Hsw + (size_t)m0 * D_MODEL + so + lane * 8, &Hs[so]);
  }
#pragma unroll
  for (int j = 0; j < 16; j++) {
    int so = __builtin_amdgcn_readfirstlane((w * 16 + j) * 512);
    g2lds16(w1i + so + lane * 8, &Wsh[so]);
  }
  __syncthreads();

  // ---- GEMM1 in two n1-halves (Wsh = 128 rows of W1 at a time) ----
#pragma unroll 1
  for (int half = 0; half < 2; half++) {
    f32x4 a1[2][4];
#pragma unroll
    for (int i = 0; i < 2; i++)
#pragma unroll
      for (int j = 0; j < 4; j++) a1[i][j] = (f32x4){0.f, 0.f, 0.f, 0.f};
#pragma unroll
    for (int kf = 0; kf < 8; kf++) {
      bf16x8 fh[2], fw1[4];
#pragma unroll
      for (int i = 0; i < 2; i++)
        fh[i] = as_bf8(*(short8*)&Hs[(mh * 32 + i * 16 + l15) * 256 + kf * 32 +
                                     ((quad ^ (l15 & 3)) * 8)]);
#pragma unroll
      for (int i = 0; i < 4; i++)
        fw1[i] = as_bf8(*(short8*)&Wsh[(nq * 64 + i * 16 + l15) * 256 + kf * 32 +
                                       ((quad ^ (l15 & 3)) * 8)]);
#pragma unroll
      for (int mt = 0; mt < 2; mt++)
#pragma unroll
        for (int nt = 0; nt < 4; nt++)
          a1[mt][nt] = __builtin_amdgcn_mfma_f32_16x16x32_bf16(fw1[nt], fh[mt], a1[mt][nt], 0, 0, 0);
    }
#pragma unroll
    for (int mt = 0; mt < 2; mt++)
#pragma unroll
      for (int nt = 0; nt < 4; nt++) {
        int n1 = half * 128 + nq * 64 + nt * 16 + quad * 4;
        int ml = mh * 32 + mt * 16 + l15;
        float4 bv = *(const float4*)(bf1 + n1);
        f32x4 v = a1[mt][nt];
        short4v o = {f2bf(fmaxf(v[0] + bv.x, 0.f)), f2bf(fmaxf(v[1] + bv.y, 0.f)),
                     f2bf(fmaxf(v[2] + bv.z, 0.f)), f2bf(fmaxf(v[3] + bv.w, 0.f))};
        *(short4v*)&F1s[ml * 264 + n1] = o;
      }
    __syncthreads();
    const short* nsrc = (half == 0) ? (w1i + 128 * 256) : w2i;
#pragma unroll
    for (int j = 0; j < 16; j++) {
      int so = __builtin_amdgcn_readfirstlane((w * 16 + j) * 512);
      g2lds16(nsrc + so + lane * 8, &Wsh[so]);
    }
    __syncthreads();
  }

  // ---- GEMM2 in two n2-halves ----
#pragma unroll 1
  for (int half = 0; half < 2; half++) {
    f32x4 a2[2][4];
#pragma unroll
    for (int i = 0; i < 2; i++)
#pragma unroll
      for (int j = 0; j < 4; j++) a2[i][j] = (f32x4){0.f, 0.f, 0.f, 0.f};
#pragma unroll
    for (int kf = 0; kf < 8; kf++) {
      bf16x8 ff[2], fw2[4];
#pragma unroll
      for (int i = 0; i < 2; i++)
        ff[i] = as_bf8(*(short8*)&F1s[(mh * 32 + i * 16 + l15) * 264 + kf * 32 + quad * 8]);
#pragma unroll
      for (int i = 0; i < 4; i++)
        fw2[i] = as_bf8(*(short8*)&Wsh[(nq * 64 + i * 16 + l15) * 256 + kf * 32 +
                                       ((quad ^ (l15 & 3)) * 8)]);
#pragma unroll
      for (int mt = 0; mt < 2; mt++)
#pragma unroll
        for (int nt = 0; nt < 4; nt++)
          a2[mt][nt] = __builtin_amdgcn_mfma_f32_16x16x32_bf16(ff[mt], fw2[nt], a2[mt][nt], 0, 0, 0);
    }
#pragma unroll
    for (int mt = 0; mt < 2; mt++)
#pragma unroll
      for (int nt = 0; nt < 4; nt++) {
        int n2 = half * 128 + nq * 64 + nt * 16 + l15;
        int mg = m0 + mh * 32 + mt * 16 + quad * 4;
        float bv = bf2[n2];
        f32x4 v = a2[mt][nt];
#pragma unroll
        for (int r = 0; r < 4; r++) {
          size_t a = (size_t)(mg + r) * D_MODEL + n2;
          out[a] = v[r] + bv + xt[a];
        }
      }
    if (half == 0) {
      __syncthreads();
#pragma unroll
      for (int j = 0; j < 16; j++) {
        int so = __builtin_amdgcn_readfirstlane((w * 16 + j) * 512);
        g2lds16(w2i + 128 * 256 + so + lane * 8, &Wsh[so]);
      }
      __syncthreads();
    }
  }
}

// ---- MFMA flash attention: singleton 64-q tiles, long-first, 1024 blocks --
__global__ __launch_bounds__(256) void attn_v3(const short* __restrict__ qb,
                                               const short* __restrict__ kimg,
                                               const short* __restrict__ vimg,
                                               const float* __restrict__ x,
                                               float* __restrict__ xt) {
  __shared__ __align__(16) short Ks[2 * 4096];
  __shared__ __align__(16) short Vs[2 * 4096];
  __shared__ __align__(16) short Pt[4][16 * 136];

  const int t = threadIdx.x, lane = t & 63, w = t >> 6;
  const int quad = lane >> 4, l15 = lane & 15;
  const int bh = blockIdx.y, b = bh >> 2, h = bh & 3;
  const int ldsoff = __builtin_amdgcn_readfirstlane(w * 512);
  const short* kb_bh = kimg + (size_t)bh * 64 * 4096;
  const short* vb_bh = vimg + (size_t)bh * 64 * 4096;

  const int qt = 63 - (int)blockIdx.x;  // long blocks dispatched first
  const int q0 = qt * 64;
  const int qrow = q0 + w * 16 + l15;
  const int wq_lo = q0 + w * 16, wq_hi = wq_lo + 15;

  bf16x8 qf0, qf1;
  {
    const short* qp = qb + ((size_t)(b * SEQ + qrow)) * D_MODEL + h * HEAD_DIM + quad * 8;
    qf0 = as_bf8(*(const short8*)qp);
    qf1 = as_bf8(*(const short8*)(qp + 32));
  }
  f32x4 oacc[4];
#pragma unroll
  for (int i = 0; i < 4; i++) oacc[i] = (f32x4){0.f, 0.f, 0.f, 0.f};
  float mrun = -1e30f, lrun = 0.f;

  const int niter = (qt + 2) >> 1;
  for (int it = 0; it < niter; it++) {
    const int j0 = it * 128;
    const short* kc_base = kb_bh + (size_t)(2 * it) * 4096;
    const short* vc_base = vb_bh + (size_t)(2 * it) * 4096;
#pragma unroll
    for (int i = 0; i < 4; i++) {
      g2lds16(kc_base + i * 2048 + t * 8, &Ks[i * 2048 + ldsoff]);
      g2lds16(vc_base + i * 2048 + t * 8, &Vs[i * 2048 + ldsoff]);
    }
    __syncthreads();

    const bool half1 = (j0 + 64) <= wq_hi;
    const int kcmax = half1 ? 8 : 4;
    f32x4 st[8];
#pragma unroll
    for (int kc = 0; kc < 8; kc++) {
      if (kc < kcmax) {
        int key = kc * 16 + l15;
        int img = (key >> 6) * 4096, r = key & 63;
        f32x4 z = (f32x4){0.f, 0.f, 0.f, 0.f};
        bf16x8 kf0 = as_bf8(*(short8*)&Ks[img + r * 64 + ((quad ^ (r & 7)) * 8)]);
        bf16x8 kf1 = as_bf8(*(short8*)&Ks[img + r * 64 + (((4 + quad) ^ (r & 7)) * 8)]);
        z = __builtin_amdgcn_mfma_f32_16x16x32_bf16(kf0, qf0, z, 0, 0, 0);
        z = __builtin_amdgcn_mfma_f32_16x16x32_bf16(kf1, qf1, z, 0, 0, 0);
        st[kc] = z;
      } else {
        st[kc] = (f32x4){-1e30f, -1e30f, -1e30f, -1e30f};
      }
    }
    if (j0 + 127 > wq_lo) {
#pragma unroll
      for (int kc = 0; kc < 8; kc++)
#pragma unroll
        for (int r = 0; r < 4; r++)
          if (j0 + kc * 16 + quad * 4 + r > qrow) st[kc][r] = -1e30f;
    }
    float smax = -1e30f;
#pragma unroll
    for (int kc = 0; kc < 8; kc++)
#pragma unroll
      for (int r = 0; r < 4; r++) smax = fmaxf(smax, st[kc][r]);
    smax = fmaxf(smax, __shfl_xor(smax, 16));
    smax = fmaxf(smax, __shfl_xor(smax, 32));
    float mn = fmaxf(mrun, smax);
    float alpha = __builtin_amdgcn_exp2f(mrun - mn);
    mrun = mn;
    float psum = 0.f;
#pragma unroll
    for (int kc = 0; kc < 8; kc++) {
      if (kc < kcmax) {
#pragma unroll
        for (int r = 0; r < 4; r++) {
          float p = __builtin_amdgcn_exp2f(st[kc][r] - mn);
          st[kc][r] = p;
          psum += p;
        }
      }
    }
    psum += __shfl_xor(psum, 16);
    psum += __shfl_xor(psum, 32);
    lrun = lrun * alpha + psum;
#pragma unroll
    for (int i = 0; i < 4; i++) oacc[i] *= alpha;
#pragma unroll
    for (int kc = 0; kc < 8; kc++) {
      if (kc < kcmax) {
        unsigned u0 = (__float_as_uint(st[kc][0]) >> 16) | (__float_as_uint(st[kc][1]) & 0xffff0000u);
        unsigned u1 = (__float_as_uint(st[kc][2]) >> 16) | (__float_as_uint(st[kc][3]) & 0xffff0000u);
        uint2 uu = {u0, u1};
        *(uint2*)&Pt[w][l15 * 136 + kc * 16 + quad * 4] = uu;
      }
    }
    const int fimax = half1 ? 4 : 2;
    bf16x8 pf[4];
#pragma unroll
    for (int fi = 0; fi < 4; fi++)
      if (fi < fimax) pf[fi] = as_bf8(*(short8*)&Pt[w][l15 * 136 + fi * 32 + quad * 8]);
#pragma unroll
    for (int dt = 0; dt < 4; dt++) {
      f32x4 o = oacc[dt];
      int d = dt * 16 + l15;
#pragma unroll
      for (int fi = 0; fi < 4; fi++) {
        if (fi < fimax) {
          bf16x8 vf = as_bf8(*(short8*)&Vs[(fi >> 1) * 4096 + d * 64 +
                                           ((((fi & 1) * 4 + quad) ^ (d & 7)) * 8)]);
          o = __builtin_amdgcn_mfma_f32_16x16x32_bf16(vf, pf[fi], o, 0, 0, 0);
        }
      }
      oacc[dt] = o;
    }
    __syncthreads();
  }

  float inv = 1.0f / lrun;
  size_t rowb = ((size_t)(b * SEQ + qrow)) * D_MODEL + h * HEAD_DIM;
#pragma unroll
  for (int dt = 0; dt < 4; dt++) {
    size_t a = rowb + dt * 16 + quad * 4;
    float4 xv = *(const float4*)(x + a);
    float4 o = make_float4(oacc[dt][0] * inv + xv.x, oacc[dt][1] * inv + xv.y,
                           oacc[dt][2] * inv + xv.z, oacc[dt][3] * inv + xv.w);
    *(float4*)(xt + a) = o;
  }
}

// ---------------------------------------------------------------------------
extern "C" void kernel_launch(void* const* d_in, const int* in_sizes, int n_in,
                              void* d_out, int out_size, void* d_ws,
                              size_t ws_size, hipStream_t stream) {
  const float* x = (const float*)d_in[0];
  const float* Wq = (const float*)d_in[1];
  const float* Wk = (const float*)d_in[2];
  const float* Wv = (const float*)d_in[3];
  const float* g1 = (const float*)d_in[4];
  const float* b1 = (const float*)d_in[5];
  const float* g2 = (const float*)d_in[6];
  const float* b2 = (const float*)d_in[7];
  const float* W1 = (const float*)d_in[8];
  const float* bf1 = (const float*)d_in[9];
  const float* W2 = (const float*)d_in[10];
  const float* bf2 = (const float*)d_in[11];
  float* out = (float*)d_out;

  char* ws = (char*)d_ws;
  float* xt = (float*)ws;                       // 16 MB
  short* q_bf = (short*)(ws + (16u << 20));     // 8 MB
  short* kimg = (short*)(ws + (24u << 20));     // 8 MB
  short* vimg = (short*)(ws + (32u << 20));     // 8 MB
  short* xn_sw = (short*)(ws + (40u << 20));    // 8 MB (xn, then h)
  short* wq_i = (short*)(ws + (48u << 20));     // 5 x 128 KB swizzled weights
  short* wk_i = wq_i + 65536;
  short* wv_i = wq_i + 2 * 65536;
  short* w1_i = wq_i + 3 * 65536;
  short* w2_i = wq_i + 4 * 65536;

  dim3 blk(256);
  wcvt<<<160, blk, 0, stream>>>(Wq, Wk, Wv, W1, W2, wq_i, wk_i, wv_i, w1_i, w2_i);
  ln_sw<<<MROWS / 8, blk, 0, stream>>>(x, g1, b1, xn_sw);
  qkv_oneshot<<<dim3(MROWS / 64, 12), blk, 0, stream>>>(wq_i, wk_i, wv_i, xn_sw,
                                                        q_bf, kimg, vimg);
  attn_v3<<<dim3(64, 16), blk, 0, stream>>>(q_bf, kimg, vimg, x, xt);
  ln_sw<<<MROWS / 8, blk, 0, stream>>>(xt, g2, b2, xn_sw);
  ffn_oneshot<<<MROWS / 64, blk, 0, stream>>>(w1_i, w2_i, xn_sw, bf1, bf2, xt, out);
}

// Round 8
// 206.562 us; speedup vs baseline: 1.3410x; 1.2382x over previous
//
#include <hip/hip_runtime.h>
#include <math.h>

#define D_MODEL 256
#define NHEAD 4
#define HEAD_DIM 64
#define SEQ 4096
#define BATCH 4
#define MROWS (BATCH * SEQ)

typedef __attribute__((ext_vector_type(8))) short short8;
typedef __attribute__((ext_vector_type(4))) short short4v;
typedef __attribute__((ext_vector_type(8))) __bf16 bf16x8;
typedef __attribute__((ext_vector_type(4))) float f32x4;

__device__ inline short f2bf(float f) {  // RNE fp32->bf16
  unsigned u = __float_as_uint(f);
  u += 0x7fffu + ((u >> 16) & 1u);
  return (short)(u >> 16);
}
__device__ inline bf16x8 as_bf8(short8 s) {
  union { short8 s; bf16x8 b; } u;
  u.s = s;
  return u.b;
}
// async global->LDS, 16B per lane; LDS dest = wave-uniform base + lane*16
__device__ __forceinline__ void g2lds16(const void* g, void* l) {
  __builtin_amdgcn_global_load_lds(
      (const __attribute__((address_space(1))) unsigned int*)g,
      (__attribute__((address_space(3))) unsigned int*)l, 16, 0, 0);
}

#define QSCALE 0.1803368801111204f  /* 0.125 * log2(e): exp2-domain scores */

// ---- weight cvt fp32->bf16, row-major with XOR-swizzled 16B groups --------
// element (n,k) -> n*256 + (k>>5)*32 + (((k>>3)&3) ^ (n&3))*8 + (k&7)
__global__ __launch_bounds__(256) void wcvt(const float* __restrict__ s0, const float* __restrict__ s1,
                                            const float* __restrict__ s2, const float* __restrict__ s3,
                                            const float* __restrict__ s4, short* __restrict__ d0,
                                            short* __restrict__ d1, short* __restrict__ d2,
                                            short* __restrict__ d3, short* __restrict__ d4) {
  int mat = blockIdx.x >> 5;
  int e = ((blockIdx.x & 31) * 256 + threadIdx.x) * 8;
  const float* s = mat == 0 ? s0 : mat == 1 ? s1 : mat == 2 ? s2 : mat == 3 ? s3 : s4;
  short* d = mat == 0 ? d0 : mat == 1 ? d1 : mat == 2 ? d2 : mat == 3 ? d3 : d4;
  int n = e >> 8, k0 = e & 255;
  float4 f0 = *(const float4*)(s + n * 256 + k0);
  float4 f1 = *(const float4*)(s + n * 256 + k0 + 4);
  short8 o = {f2bf(f0.x), f2bf(f0.y), f2bf(f0.z), f2bf(f0.w),
              f2bf(f1.x), f2bf(f1.y), f2bf(f1.z), f2bf(f1.w)};
  int chunk = k0 >> 5, g = (k0 >> 3) & 3;
  *(short8*)(d + n * 256 + chunk * 32 + ((g ^ (n & 3)) * 8)) = o;
}

// ---- LayerNorm fp32 -> bf16 swizzled rows (8 rows/block, 32 thr/row) ------
__global__ __launch_bounds__(256) void ln_sw(const float* __restrict__ x,
                                             const float* __restrict__ g,
                                             const float* __restrict__ b,
                                             short* __restrict__ o) {
  int r = threadIdx.x >> 5, c8 = threadIdx.x & 31;
  int row = blockIdx.x * 8 + r;
  const float* xr = x + (size_t)row * D_MODEL + c8 * 8;
  float4 a = *(const float4*)xr;
  float4 c = *(const float4*)(xr + 4);
  float s = a.x + a.y + a.z + a.w + c.x + c.y + c.z + c.w;
#pragma unroll
  for (int off = 16; off > 0; off >>= 1) s += __shfl_xor(s, off);
  float mu = s * (1.0f / D_MODEL);
  float d0 = a.x - mu, d1 = a.y - mu, d2 = a.z - mu, d3 = a.w - mu;
  float d4 = c.x - mu, d5 = c.y - mu, d6 = c.z - mu, d7 = c.w - mu;
  float ss = d0 * d0 + d1 * d1 + d2 * d2 + d3 * d3 + d4 * d4 + d5 * d5 + d6 * d6 + d7 * d7;
#pragma unroll
  for (int off = 16; off > 0; off >>= 1) ss += __shfl_xor(ss, off);
  float rstd = rsqrtf(ss * (1.0f / D_MODEL) + 1e-5f);
  float4 ga = *(const float4*)(g + c8 * 8);
  float4 gc = *(const float4*)(g + c8 * 8 + 4);
  float4 ba = *(const float4*)(b + c8 * 8);
  float4 bc = *(const float4*)(b + c8 * 8 + 4);
  short8 ov = {f2bf(d0 * rstd * ga.x + ba.x), f2bf(d1 * rstd * ga.y + ba.y),
               f2bf(d2 * rstd * ga.z + ba.z), f2bf(d3 * rstd * ga.w + ba.w),
               f2bf(d4 * rstd * gc.x + bc.x), f2bf(d5 * rstd * gc.y + bc.y),
               f2bf(d6 * rstd * gc.z + bc.z), f2bf(d7 * rstd * gc.w + bc.w)};
  int chunk = c8 >> 2, gr = c8 & 3;
  *(short8*)(o + (size_t)row * D_MODEL + chunk * 32 + ((gr ^ (row & 3)) * 8)) = ov;
}

// ---- QKV GEMM: X panel in LDS once, W fragments DIRECT from L2 image ------
// grid (256, 3): 64-row m-tile, y = which in {Q,K,V}. One barrier per block.
__global__ __launch_bounds__(256) void qkv_direct(
    const short* __restrict__ Wqi, const short* __restrict__ Wki,
    const short* __restrict__ Wvi, const short* __restrict__ Xn,
    short* __restrict__ qo, short* __restrict__ kimg, short* __restrict__ vimg) {
  __shared__ __align__(16) short Xs[64 * 256];  // 32 KB
  const int t = threadIdx.x, lane = t & 63, w = t >> 6;
  const int l15 = lane & 15, quad = lane >> 4;
  const int m0 = blockIdx.x * 64;
  const int which = blockIdx.y;
  const short* Wb = which == 0 ? Wqi : which == 1 ? Wki : Wvi;

#pragma unroll
  for (int j = 0; j < 8; j++) {
    int so = __builtin_amdgcn_readfirstlane((w * 8 + j) * 512);
    g2lds16(Xn + (size_t)m0 * D_MODEL + so + lane * 8, &Xs[so]);
  }
  __syncthreads();

  // hoisted fragment bases (all further offsets compile-time)
  const short* xb = &Xs[l15 * 256 + ((quad ^ (l15 & 3)) * 8)];
  const short* wb = Wb + (size_t)(w * 64 + l15) * 256 + ((quad ^ (l15 & 3)) * 8);

  f32x4 acc[4][4];
#pragma unroll
  for (int i = 0; i < 4; i++)
#pragma unroll
    for (int j = 0; j < 4; j++) acc[i][j] = (f32x4){0.f, 0.f, 0.f, 0.f};

#pragma unroll
  for (int kf = 0; kf < 8; kf++) {
    bf16x8 fx[4], fw[4];
#pragma unroll
    for (int i = 0; i < 4; i++) {
      fx[i] = as_bf8(*(const short8*)(xb + i * 4096 + kf * 32));
      fw[i] = as_bf8(*(const short8*)(wb + i * 4096 + kf * 32));
    }
    if (which == 2) {
#pragma unroll
      for (int mt = 0; mt < 4; mt++)
#pragma unroll
        for (int nt = 0; nt < 4; nt++)
          acc[mt][nt] = __builtin_amdgcn_mfma_f32_16x16x32_bf16(fx[mt], fw[nt], acc[mt][nt], 0, 0, 0);
    } else {
#pragma unroll
      for (int mt = 0; mt < 4; mt++)
#pragma unroll
        for (int nt = 0; nt < 4; nt++)
          acc[mt][nt] = __builtin_amdgcn_mfma_f32_16x16x32_bf16(fw[nt], fx[mt], acc[mt][nt], 0, 0, 0);
    }
  }

#pragma unroll
  for (int mt = 0; mt < 4; mt++)
#pragma unroll
    for (int nt = 0; nt < 4; nt++) {
      f32x4 v = acc[mt][nt];
      if (which == 2) {  // VT image: C[m=s][n=feature] (rows via quad*4+r)
        int n = w * 64 + nt * 16 + l15;
        int mr = m0 + mt * 16 + quad * 4;
        int b = mr >> 12, s = mr & 4095, h = n >> 6, d = n & 63;
        size_t off = ((size_t)(b * NHEAD + h) * 64 + (s >> 6)) * 4096 +
                     (size_t)d * 64 + ((((s & 63) >> 3) ^ (d & 7)) * 8) + (s & 7);
        short4v o = {f2bf(v[0]), f2bf(v[1]), f2bf(v[2]), f2bf(v[3])};
        *(short4v*)(vimg + off) = o;
      } else {  // C[n][m]: col = m via l15, row = n via quad*4+r
        int m = m0 + mt * 16 + l15;
        int nb = w * 64 + nt * 16 + quad * 4;
        if (which == 0) {  // Q row-major, exp2-domain scale folded in
          v *= QSCALE;
          short4v o = {f2bf(v[0]), f2bf(v[1]), f2bf(v[2]), f2bf(v[3])};
          *(short4v*)(qo + (size_t)m * D_MODEL + nb) = o;
        } else {  // K image
          int b = m >> 12, s = m & 4095, h = nb >> 6, d = nb & 63;
          size_t off = ((size_t)(b * NHEAD + h) * 64 + (s >> 6)) * 4096 +
                       (size_t)(s & 63) * 64 + (((d >> 3) ^ (s & 7)) * 8) + (d & 7);
          short4v o = {f2bf(v[0]), f2bf(v[1]), f2bf(v[2]), f2bf(v[3])};
          *(short4v*)(kimg + off) = o;
        }
      }
    }
}

// ---- FFN: 32-row tiles, f1 LDS-resident, W direct from L2 images ----------
// grid 512 (2+ blocks/CU), 2 barriers per block.
__global__ __launch_bounds__(256) void ffn_direct(
    const short* __restrict__ w1i, const short* __restrict__ w2i,
    const short* __restrict__ Hsw, const float* __restrict__ bf1,
    const float* __restrict__ bf2, const float* __restrict__ xt,
    float* __restrict__ out) {
  __shared__ __align__(16) short Hs[32 * 256];   // 16 KB (image layout)
  __shared__ __align__(16) short F1s[32 * 264];  // 16.5 KB (padded rows)
  const int t = threadIdx.x, lane = t & 63, w = t >> 6;
  const int l15 = lane & 15, quad = lane >> 4;
  const int m0 = blockIdx.x * 32;

#pragma unroll
  for (int j = 0; j < 4; j++) {
    int so = __builtin_amdgcn_readfirstlane((w * 4 + j) * 512);
    g2lds16(Hsw + (size_t)m0 * D_MODEL + so + lane * 8, &Hs[so]);
  }
  __syncthreads();

  const short* hb = &Hs[l15 * 256 + ((quad ^ (l15 & 3)) * 8)];
  const short* w1b = w1i + (size_t)(w * 64 + l15) * 256 + ((quad ^ (l15 & 3)) * 8);
  const short* w2b = w2i + (size_t)(w * 64 + l15) * 256 + ((quad ^ (l15 & 3)) * 8);

  // ---- GEMM1: C[n1][m] = W1 . h^T ; wave owns 64 n1, all 32 m ----
  f32x4 a1[2][4];
#pragma unroll
  for (int i = 0; i < 2; i++)
#pragma unroll
    for (int j = 0; j < 4; j++) a1[i][j] = (f32x4){0.f, 0.f, 0.f, 0.f};
#pragma unroll
  for (int kf = 0; kf < 8; kf++) {
    bf16x8 fh[2], fw1[4];
#pragma unroll
    for (int i = 0; i < 2; i++) fh[i] = as_bf8(*(const short8*)(hb + i * 4096 + kf * 32));
#pragma unroll
    for (int i = 0; i < 4; i++) fw1[i] = as_bf8(*(const short8*)(w1b + i * 4096 + kf * 32));
#pragma unroll
    for (int mt = 0; mt < 2; mt++)
#pragma unroll
      for (int nt = 0; nt < 4; nt++)
        a1[mt][nt] = __builtin_amdgcn_mfma_f32_16x16x32_bf16(fw1[nt], fh[mt], a1[mt][nt], 0, 0, 0);
  }
  // f1 = relu(D1 + bf1) -> F1s[m][n1]
#pragma unroll
  for (int mt = 0; mt < 2; mt++)
#pragma unroll
    for (int nt = 0; nt < 4; nt++) {
      int n1 = w * 64 + nt * 16 + quad * 4;
      int ml = mt * 16 + l15;
      float4 bv = *(const float4*)(bf1 + n1);
      f32x4 v = a1[mt][nt];
      short4v o = {f2bf(fmaxf(v[0] + bv.x, 0.f)), f2bf(fmaxf(v[1] + bv.y, 0.f)),
                   f2bf(fmaxf(v[2] + bv.z, 0.f)), f2bf(fmaxf(v[3] + bv.w, 0.f))};
      *(short4v*)&F1s[ml * 264 + n1] = o;
    }
  __syncthreads();

  // ---- GEMM2: C[m][n2] = f1 . W2^T ; wave owns 64 n2 ----
  const short* fb = &F1s[l15 * 264 + quad * 8];
  f32x4 a2[2][4];
#pragma unroll
  for (int i = 0; i < 2; i++)
#pragma unroll
    for (int j = 0; j < 4; j++) a2[i][j] = (f32x4){0.f, 0.f, 0.f, 0.f};
#pragma unroll
  for (int kf = 0; kf < 8; kf++) {
    bf16x8 ff[2], fw2[4];
#pragma unroll
    for (int i = 0; i < 2; i++) ff[i] = as_bf8(*(const short8*)(fb + i * 16 * 264 + kf * 32));
#pragma unroll
    for (int i = 0; i < 4; i++) fw2[i] = as_bf8(*(const short8*)(w2b + i * 4096 + kf * 32));
#pragma unroll
    for (int mt = 0; mt < 2; mt++)
#pragma unroll
      for (int nt = 0; nt < 4; nt++)
        a2[mt][nt] = __builtin_amdgcn_mfma_f32_16x16x32_bf16(ff[mt], fw2[nt], a2[mt][nt], 0, 0, 0);
  }
  // out = D2 + bf2 + xt
#pragma unroll
  for (int mt = 0; mt < 2; mt++)
#pragma unroll
    for (int nt = 0; nt < 4; nt++) {
      int n2 = w * 64 + nt * 16 + l15;
      int mg = m0 + mt * 16 + quad * 4;
      float bv = bf2[n2];
      f32x4 v = a2[mt][nt];
#pragma unroll
      for (int r = 0; r < 4; r++) {
        size_t a = (size_t)(mg + r) * D_MODEL + n2;
        out[a] = v[r] + bv + xt[a];
      }
    }
}

// ---- MFMA flash attention v4: paired tiles (33 iters/block, balanced), ----
// streaming softmax (no running max, l reduced at epilogue), hoisted addrs.
__global__ __launch_bounds__(256) void attn_v4(const short* __restrict__ qb,
                                               const short* __restrict__ kimg,
                                               const short* __restrict__ vimg,
                                               const float* __restrict__ x,
                                               float* __restrict__ xt) {
  __shared__ __align__(16) short Ks[2 * 4096];
  __shared__ __align__(16) short Vs[2 * 4096];
  __shared__ __align__(16) short Pt[4][16 * 136];

  const int t = threadIdx.x, lane = t & 63, w = t >> 6;
  const int quad = lane >> 4, l15 = lane & 15, l7 = lane & 7;
  const int pair = blockIdx.x;
  const int bh = blockIdx.y, b = bh >> 2, h = bh & 3;
  const int ldsoff = __builtin_amdgcn_readfirstlane(w * 512);
  const short* kb_bh = kimg + (size_t)bh * 64 * 4096;
  const short* vb_bh = vimg + (size_t)bh * 64 * 4096;

  // hoisted LDS fragment bases (offsets below are compile-time constants)
  const short* kb0 = &Ks[l15 * 64 + ((quad ^ l7) * 8)];
  const short* kb1 = &Ks[l15 * 64 + (((4 + quad) ^ l7) * 8)];
  const short* vb0 = &Vs[l15 * 64 + ((quad ^ l7) * 8)];
  const short* vb1 = &Vs[l15 * 64 + (((4 + quad) ^ l7) * 8)];
  short* pw = &Pt[w][l15 * 136];

  for (int tile = 0; tile < 2; tile++) {
    const int qt = tile == 0 ? 63 - pair : pair;
    const int q0 = qt * 64;
    const int qrow = q0 + w * 16 + l15;
    const int wq_lo = q0 + w * 16, wq_hi = wq_lo + 15;

    bf16x8 qf0, qf1;
    {
      const short* qp = qb + ((size_t)(b * SEQ + qrow)) * D_MODEL + h * HEAD_DIM + quad * 8;
      qf0 = as_bf8(*(const short8*)qp);
      qf1 = as_bf8(*(const short8*)(qp + 32));
    }
    f32x4 oacc[4];
#pragma unroll
    for (int i = 0; i < 4; i++) oacc[i] = (f32x4){0.f, 0.f, 0.f, 0.f};
    float lrun = 0.f;

    const int niter = (qt + 2) >> 1;
    for (int it = 0; it < niter; it++) {
      const int j0 = it * 128;
      const short* kc_base = kb_bh + (size_t)(2 * it) * 4096;
      const short* vc_base = vb_bh + (size_t)(2 * it) * 4096;
#pragma unroll
      for (int i = 0; i < 4; i++) {
        g2lds16(kc_base + i * 2048 + t * 8, &Ks[i * 2048 + ldsoff]);
        g2lds16(vc_base + i * 2048 + t * 8, &Vs[i * 2048 + ldsoff]);
      }
      __syncthreads();

      const bool half1 = (j0 + 64) <= wq_hi;  // wave-uniform
      const int kcmax = half1 ? 8 : 4;
      f32x4 st[8];
#pragma unroll
      for (int kc = 0; kc < 8; kc++) {
        if (kc < kcmax) {
          f32x4 z = (f32x4){0.f, 0.f, 0.f, 0.f};
          bf16x8 kf0 = as_bf8(*(const short8*)(kb0 + (kc & 3) * 1024 + (kc >> 2) * 4096));
          bf16x8 kf1 = as_bf8(*(const short8*)(kb1 + (kc & 3) * 1024 + (kc >> 2) * 4096));
          z = __builtin_amdgcn_mfma_f32_16x16x32_bf16(kf0, qf0, z, 0, 0, 0);
          z = __builtin_amdgcn_mfma_f32_16x16x32_bf16(kf1, qf1, z, 0, 0, 0);
          st[kc] = z;
        }
      }
      // causal mask via sentinel (exp2 -> 0) on diagonal-overlapping iters
      if (j0 + 127 > wq_lo) {
#pragma unroll
        for (int kc = 0; kc < 8; kc++)
          if (kc < kcmax) {
#pragma unroll
            for (int r = 0; r < 4; r++)
              if (j0 + kc * 16 + quad * 4 + r > qrow) st[kc][r] = -1e30f;
          }
      }
      // streaming softmax: p = exp2(s) unnormalized; l accumulated per-lane
#pragma unroll
      for (int kc = 0; kc < 8; kc++) {
        if (kc < kcmax) {
#pragma unroll
          for (int r = 0; r < 4; r++) {
            float p = __builtin_amdgcn_exp2f(st[kc][r]);
            st[kc][r] = p;
            lrun += p;
          }
          unsigned u0 = (__float_as_uint(st[kc][0]) >> 16) | (__float_as_uint(st[kc][1]) & 0xffff0000u);
          unsigned u1 = (__float_as_uint(st[kc][2]) >> 16) | (__float_as_uint(st[kc][3]) & 0xffff0000u);
          uint2 uu = {u0, u1};
          *(uint2*)(pw + kc * 16 + quad * 4) = uu;
        }
      }
      const int fimax = half1 ? 4 : 2;
      bf16x8 pf[4];
#pragma unroll
      for (int fi = 0; fi < 4; fi++)
        if (fi < fimax) pf[fi] = as_bf8(*(const short8*)(pw + fi * 32 + quad * 8));
#pragma unroll
      for (int dt = 0; dt < 4; dt++) {
        f32x4 o = oacc[dt];
#pragma unroll
        for (int fi = 0; fi < 4; fi++) {
          if (fi < fimax) {
            const short* va = (fi & 1) ? vb1 : vb0;
            bf16x8 vf = as_bf8(*(const short8*)(va + dt * 1024 + (fi >> 1) * 4096));
            o = __builtin_amdgcn_mfma_f32_16x16x32_bf16(vf, pf[fi], o, 0, 0, 0);
          }
        }
        oacc[dt] = o;
      }
      __syncthreads();
    }

    // epilogue: reduce l across the 4 quad groups, then xt = x + O^T / l
    lrun += __shfl_xor(lrun, 16);
    lrun += __shfl_xor(lrun, 32);
    float inv = 1.0f / lrun;
    size_t rowb = ((size_t)(b * SEQ + qrow)) * D_MODEL + h * HEAD_DIM;
#pragma unroll
    for (int dt = 0; dt < 4; dt++) {
      size_t a = rowb + dt * 16 + quad * 4;
      float4 xv = *(const float4*)(x + a);
      float4 o = make_float4(oacc[dt][0] * inv + xv.x, oacc[dt][1] * inv + xv.y,
                             oacc[dt][2] * inv + xv.z, oacc[dt][3] * inv + xv.w);
      *(float4*)(xt + a) = o;
    }
  }
}

// ---------------------------------------------------------------------------
extern "C" void kernel_launch(void* const* d_in, const int* in_sizes, int n_in,
                              void* d_out, int out_size, void* d_ws,
                              size_t ws_size, hipStream_t stream) {
  const float* x = (const float*)d_in[0];
  const float* Wq = (const float*)d_in[1];
  const float* Wk = (const float*)d_in[2];
  const float* Wv = (const float*)d_in[3];
  const float* g1 = (const float*)d_in[4];
  const float* b1 = (const float*)d_in[5];
  const float* g2 = (const float*)d_in[6];
  const float* b2 = (const float*)d_in[7];
  const float* W1 = (const float*)d_in[8];
  const float* bf1 = (const float*)d_in[9];
  const float* W2 = (const float*)d_in[10];
  const float* bf2 = (const float*)d_in[11];
  float* out = (float*)d_out;

  char* ws = (char*)d_ws;
  float* xt = (float*)ws;                       // 16 MB
  short* q_bf = (short*)(ws + (16u << 20));     // 8 MB
  short* kimg = (short*)(ws + (24u << 20));     // 8 MB
  short* vimg = (short*)(ws + (32u << 20));     // 8 MB
  short* xn_sw = (short*)(ws + (40u << 20));    // 8 MB (xn, then h)
  short* wq_i = (short*)(ws + (48u << 20));     // 5 x 128 KB swizzled weights
  short* wk_i = wq_i + 65536;
  short* wv_i = wq_i + 2 * 65536;
  short* w1_i = wq_i + 3 * 65536;
  short* w2_i = wq_i + 4 * 65536;

  dim3 blk(256);
  wcvt<<<160, blk, 0, stream>>>(Wq, Wk, Wv, W1, W2, wq_i, wk_i, wv_i, w1_i, w2_i);
  ln_sw<<<MROWS / 8, blk, 0, stream>>>(x, g1, b1, xn_sw);
  qkv_direct<<<dim3(MROWS / 64, 3), blk, 0, stream>>>(wq_i, wk_i, wv_i, xn_sw,
                                                      q_bf, kimg, vimg);
  attn_v4<<<dim3(32, 16), blk, 0, stream>>>(q_bf, kimg, vimg, x, xt);
  ln_sw<<<MROWS / 8, blk, 0, stream>>>(xt, g2, b2, xn_sw);
  ffn_direct<<<MROWS / 32, blk, 0, stream>>>(w1_i, w2_i, xn_sw, bf1, bf2, xt, out);
}